// Round 10
// baseline (112.425 us; speedup 1.0000x reference)
//
#include <hip/hip_runtime.h>
#include <math.h>

// ECE loss: per-row softmax-max confidence + argmax prediction, binned
// histogram over (pred_class, conf_bin) cells, ECE = sum|sum_conf-sum_acc|/N.
//
// Round-10 = round-9 (NT staging, 85.75 us) + occupancy lever: 32-row tiles
// (13.3 KB stage + 12 KB hist = 25.3 KB LDS) -> 6 blocks/CU, 24 waves/CU
// (was 4 blocks/16 waves). More independent stage streams per CU cover each
// block's serial consume phase. Consume: oct-per-row (8 lanes/row). Stage
// source offsets precomputed (tile-invariant). NT on labels too.
//
// N = 1,000,000 = 32 * 31250 exactly.
// Workspace (d_ws as float*): [0..NCELLS) sum_conf, [NCELLS..2*NCELLS) sum_acc.

constexpr int C  = 100;
constexpr int NB = 15;
constexpr int NCELLS = C * NB;          // 1500
constexpr int ROWS = 32;                // rows per tile
constexpr int F4R  = 25;                // float4 per row
constexpr int STR  = 26;                // padded LDS row stride (416 B)
constexpr int TILE_F4 = ROWS * STR;     // 832
constexpr int THREADS = 256;
constexpr int GRID_MAIN = 1536;         // 6 blocks/CU x 256 CU

__global__ void ece_zero(float* __restrict__ ws, int n) {
    int i = blockIdx.x * blockDim.x + threadIdx.x;
    if (i < n) ws[i] = 0.0f;
}

__device__ __forceinline__ void load_lds_16B_nt(const void* gsrc, void* ldst) {
    // aux=2: CPol NT (non-temporal) on gfx950 — stream, evict-first.
    __builtin_amdgcn_global_load_lds(
        (const __attribute__((address_space(1))) void*)gsrc,
        (__attribute__((address_space(3))) void*)ldst, 16, 0, 2);
}

__global__ __launch_bounds__(THREADS)
void ece_main(const float* __restrict__ logits,
              const int* __restrict__ labels,
              int ntiles, float* __restrict__ cellsums) {
    __shared__ float4 stage[TILE_F4];     // 13312 B
    __shared__ float  hist[2 * NCELLS];   // 12000 B -> 25.3 KB, 6 blocks/CU

    for (int i = threadIdx.x; i < 2 * NCELLS; i += THREADS) hist[i] = 0.0f;

    const int tid = threadIdx.x;
    const int o   = tid >> 3;             // row in tile (0..31)
    const int j   = tid & 7;              // lane within oct
    const int wbase = (tid >> 6) << 6;    // wave-uniform slot base

    // tile-invariant stage descriptors: slot s=i*256+tid -> (r=s/26, c=s%26);
    // c==25 is pad (skip); source f4 offset = r*25+c from tile base.
    int offs[4]; bool val[4];
    #pragma unroll
    for (int i = 0; i < 4; ++i) {
        int s = i * 256 + tid;
        int r = s / STR, c = s - r * STR;
        val[i]  = (s < TILE_F4) && (c < F4R);
        offs[i] = r * F4R + c;
    }

    const float4* logits4 = reinterpret_cast<const float4*>(logits);
    constexpr float LOG2E = 1.4426950408889634f;

    for (int tile = blockIdx.x; tile < ntiles; tile += gridDim.x) {
        const int row0 = tile * ROWS;
        const float4* tb = logits4 + (size_t)row0 * F4R;

        // ---- stage: contiguous NT stream -> padded LDS tile ----
        #pragma unroll
        for (int i = 0; i < 4; ++i) {
            if (val[i]) load_lds_16B_nt(tb + offs[i], &stage[i * 256 + wbase]);
        }
        __syncthreads();   // tile staged (vmcnt drained by barrier semantics)

        // ---- consume: oct (8 lanes) per row ----
        const int row = row0 + o;
        int lab = -1;
        if (j == 0) lab = __builtin_nontemporal_load(&labels[row]);

        const float4* rp = &stage[o * STR];
        float4 v0 = rp[j], v1 = rp[j + 8], v2 = rp[j + 16];
        float4 v3;
        const bool tail = (j == 0);
        if (tail) v3 = rp[24];

        // per-lane max + first-occurrence argmax (ascending index order)
        float m = v0.x; int am = 4 * j;
        if (v0.y > m) { m = v0.y; am = 4 * j + 1; }
        if (v0.z > m) { m = v0.z; am = 4 * j + 2; }
        if (v0.w > m) { m = v0.w; am = 4 * j + 3; }
        if (v1.x > m) { m = v1.x; am = 32 + 4 * j; }
        if (v1.y > m) { m = v1.y; am = 32 + 4 * j + 1; }
        if (v1.z > m) { m = v1.z; am = 32 + 4 * j + 2; }
        if (v1.w > m) { m = v1.w; am = 32 + 4 * j + 3; }
        if (v2.x > m) { m = v2.x; am = 64 + 4 * j; }
        if (v2.y > m) { m = v2.y; am = 64 + 4 * j + 1; }
        if (v2.z > m) { m = v2.z; am = 64 + 4 * j + 2; }
        if (v2.w > m) { m = v2.w; am = 64 + 4 * j + 3; }
        if (tail) {
            if (v3.x > m) { m = v3.x; am = 96; }
            if (v3.y > m) { m = v3.y; am = 97; }
            if (v3.z > m) { m = v3.z; am = 98; }
            if (v3.w > m) { m = v3.w; am = 99; }
        }
        #pragma unroll
        for (int off = 1; off < 8; off <<= 1) {
            float om  = __shfl_xor(m, off, 64);
            int   oam = __shfl_xor(am, off, 64);
            if (om > m || (om == m && oam < am)) { m = om; am = oam; }
        }

        // sum exp(x-m) = exp2(x*log2e - m*log2e)
        const float ml = m * LOG2E;
        float s = exp2f(__fmaf_rn(v0.x, LOG2E, -ml))
                + exp2f(__fmaf_rn(v0.y, LOG2E, -ml))
                + exp2f(__fmaf_rn(v0.z, LOG2E, -ml))
                + exp2f(__fmaf_rn(v0.w, LOG2E, -ml));
        s += exp2f(__fmaf_rn(v1.x, LOG2E, -ml))
           + exp2f(__fmaf_rn(v1.y, LOG2E, -ml))
           + exp2f(__fmaf_rn(v1.z, LOG2E, -ml))
           + exp2f(__fmaf_rn(v1.w, LOG2E, -ml));
        s += exp2f(__fmaf_rn(v2.x, LOG2E, -ml))
           + exp2f(__fmaf_rn(v2.y, LOG2E, -ml))
           + exp2f(__fmaf_rn(v2.z, LOG2E, -ml))
           + exp2f(__fmaf_rn(v2.w, LOG2E, -ml));
        if (tail) {
            s += exp2f(__fmaf_rn(v3.x, LOG2E, -ml))
               + exp2f(__fmaf_rn(v3.y, LOG2E, -ml))
               + exp2f(__fmaf_rn(v3.z, LOG2E, -ml))
               + exp2f(__fmaf_rn(v3.w, LOG2E, -ml));
        }
        #pragma unroll
        for (int off = 1; off < 8; off <<= 1) s += __shfl_xor(s, off, 64);

        if (j == 0) {
            float conf = 1.0f / s;
            int b = (int)ceilf(conf * (float)NB) - 1;
            b = b < 0 ? 0 : (b > NB - 1 ? NB - 1 : b);
            int cell = am * NB + b;
            atomicAdd(&hist[cell], conf);
            if (lab == am) atomicAdd(&hist[NCELLS + cell], 1.0f);
        }
        __syncthreads();   // protect stage buffer before next overwrite
    }

    // flush per-block histogram
    for (int i = threadIdx.x; i < 2 * NCELLS; i += THREADS) {
        float v = hist[i];
        if (v != 0.0f) atomicAdd(&cellsums[i], v);
    }
}

__global__ void ece_final(const float* __restrict__ cellsums,
                          float invN, float* __restrict__ out) {
    __shared__ float red[256];
    float t = 0.0f;
    for (int i = threadIdx.x; i < NCELLS; i += blockDim.x)
        t += fabsf(cellsums[i] - cellsums[NCELLS + i]);
    red[threadIdx.x] = t;
    __syncthreads();
    for (int w = 128; w > 0; w >>= 1) {
        if (threadIdx.x < w) red[threadIdx.x] += red[threadIdx.x + w];
        __syncthreads();
    }
    if (threadIdx.x == 0) out[0] = red[0] * invN;
}

extern "C" void kernel_launch(void* const* d_in, const int* in_sizes, int n_in,
                              void* d_out, int out_size, void* d_ws, size_t ws_size,
                              hipStream_t stream) {
    const float* logits = (const float*)d_in[0];
    const int*   labels = (const int*)d_in[1];

    const int N = in_sizes[1];            // 1,000,000 (divisible by ROWS=32)
    const int ntiles = N / ROWS;          // 31250

    float* cellsums = (float*)d_ws;
    float* out = (float*)d_out;

    // 1) zero global cell accumulators (harness poisons ws, never re-zeroes)
    {
        int n = 2 * NCELLS;
        ece_zero<<<(n + 255) / 256, 256, 0, stream>>>(cellsums, n);
    }

    // 2) main pass: NT staging, 6 blocks/CU
    ece_main<<<GRID_MAIN, THREADS, 0, stream>>>(logits, labels, ntiles, cellsums);

    // 3) finalize
    ece_final<<<1, 256, 0, stream>>>(cellsums, 1.0f / (float)N, out);
}

// Round 11
// 84.121 us; speedup vs baseline: 1.3365x; 1.3365x over previous
//
#include <hip/hip_runtime.h>
#include <math.h>

// ECE loss: per-row softmax-max confidence + argmax prediction, binned
// histogram over (pred_class, conf_bin) cells, ECE = sum|sum_conf-sum_acc|/N.
//
// Round-11 = round-9 (NT staging, 85.75 us) with the tile-size lever pushed
// the OTHER way: r10 halved the tile (13 KB/barrier) and BW fell 5.0->3.7
// TB/s; bytes-per-barrier-drain correlates with BW. Here: 512-thread blocks,
// 128-row tiles (53.2 KB stage + 12 KB hist = 65.2 KB -> 2 blocks/CU =
// 16 waves/CU, SAME occupancy as r9), half as many __syncthreads vmcnt
// drains per byte. NT staging and quad-per-row consume unchanged from r9.
//
// N = 1,000,000; 128-row tiles -> 7813 tiles, last tile 64 rows (guarded).
// Workspace (d_ws as float*): [0..NCELLS) sum_conf, [NCELLS..2*NCELLS) sum_acc.

constexpr int C  = 100;
constexpr int NB = 15;
constexpr int NCELLS = C * NB;          // 1500
constexpr int ROWS = 128;               // rows per tile
constexpr int F4R  = 25;                // float4 per row
constexpr int STR  = 26;                // padded LDS row stride (416 B)
constexpr int TILE_F4 = ROWS * STR;     // 3328
constexpr int THREADS = 512;
constexpr int GRID_MAIN = 512;          // 2 blocks/CU x 256 CU

__global__ void ece_zero(float* __restrict__ ws, int n) {
    int i = blockIdx.x * blockDim.x + threadIdx.x;
    if (i < n) ws[i] = 0.0f;
}

__device__ __forceinline__ void load_lds_16B_nt(const void* gsrc, void* ldst) {
    // aux=2: CPol NT (non-temporal) on gfx950 — stream, evict-first.
    __builtin_amdgcn_global_load_lds(
        (const __attribute__((address_space(1))) void*)gsrc,
        (__attribute__((address_space(3))) void*)ldst, 16, 0, 2);
}

__global__ __launch_bounds__(THREADS)
void ece_main(const float* __restrict__ logits,
              const int* __restrict__ labels,
              int N, int ntiles, float* __restrict__ cellsums) {
    __shared__ float4 stage[TILE_F4];     // 53248 B
    __shared__ float  hist[2 * NCELLS];   // 12000 B -> 65.2 KB, 2 blocks/CU

    for (int i = threadIdx.x; i < 2 * NCELLS; i += THREADS) hist[i] = 0.0f;

    const int tid  = threadIdx.x;
    const int l4   = tid & 3;
    const int qg   = tid >> 2;            // 0..127: row-in-tile owned by quad
    const int wbase = (tid >> 6) << 6;    // wave-uniform slot base

    // Tile-invariant stage descriptors: slot s = i*512+tid -> (r=s/26, c=s%26);
    // c==25 is pad (skip). Source f4 offset r*25+c; rrow kept for the N-guard.
    int offs[7], rrow[7]; bool val[7];
    #pragma unroll
    for (int i = 0; i < 7; ++i) {
        int s = i * 512 + tid;
        int r = s / STR, c = s - r * STR;
        val[i]  = (s < TILE_F4) && (c < F4R);
        offs[i] = r * F4R + c;
        rrow[i] = r;
    }

    const float4* logits4 = reinterpret_cast<const float4*>(logits);
    constexpr float LOG2E = 1.4426950408889634f;

    for (int tile = blockIdx.x; tile < ntiles; tile += gridDim.x) {
        const int row0 = tile * ROWS;
        const float4* tb = logits4 + (size_t)row0 * F4R;

        // ---- stage: contiguous NT stream -> padded LDS tile ----
        #pragma unroll
        for (int i = 0; i < 7; ++i) {
            if (val[i] && (row0 + rrow[i]) < N)
                load_lds_16B_nt(tb + offs[i], &stage[i * 512 + wbase]);
        }
        __syncthreads();   // tile staged

        // ---- consume: quad (4 lanes) per row ----
        const int row = row0 + qg;
        if (row < N) {
            int lab = -1;
            if (l4 == 0) lab = __builtin_nontemporal_load(&labels[row]);

            const float4* rp = &stage[qg * STR];
            float4 v[6];
            #pragma unroll
            for (int j = 0; j < 6; ++j) v[j] = rp[l4 + 4 * j];
            float4 v6;
            const bool has7 = (l4 == 0);
            if (has7) v6 = rp[24];

            // pass 1: per-lane max + first-occurrence argmax
            float m = -INFINITY;
            int   am = 0;
            #pragma unroll
            for (int j = 0; j < 6; ++j) {
                int base = (l4 + 4 * j) * 4;
                if (v[j].x > m) { m = v[j].x; am = base + 0; }
                if (v[j].y > m) { m = v[j].y; am = base + 1; }
                if (v[j].z > m) { m = v[j].z; am = base + 2; }
                if (v[j].w > m) { m = v[j].w; am = base + 3; }
            }
            if (has7) {
                if (v6.x > m) { m = v6.x; am = 96; }
                if (v6.y > m) { m = v6.y; am = 97; }
                if (v6.z > m) { m = v6.z; am = 98; }
                if (v6.w > m) { m = v6.w; am = 99; }
            }
            #pragma unroll
            for (int off = 1; off < 4; off <<= 1) {
                float om  = __shfl_xor(m, off, 64);
                int   oam = __shfl_xor(am, off, 64);
                if (om > m || (om == m && oam < am)) { m = om; am = oam; }
            }

            // pass 2: sum exp(x-m) = exp2(x*log2e - m*log2e)
            const float ml = m * LOG2E;
            float s = 0.0f;
            #pragma unroll
            for (int j = 0; j < 6; ++j) {
                s += exp2f(__fmaf_rn(v[j].x, LOG2E, -ml))
                   + exp2f(__fmaf_rn(v[j].y, LOG2E, -ml))
                   + exp2f(__fmaf_rn(v[j].z, LOG2E, -ml))
                   + exp2f(__fmaf_rn(v[j].w, LOG2E, -ml));
            }
            if (has7) {
                s += exp2f(__fmaf_rn(v6.x, LOG2E, -ml))
                   + exp2f(__fmaf_rn(v6.y, LOG2E, -ml))
                   + exp2f(__fmaf_rn(v6.z, LOG2E, -ml))
                   + exp2f(__fmaf_rn(v6.w, LOG2E, -ml));
            }
            #pragma unroll
            for (int off = 1; off < 4; off <<= 1) s += __shfl_xor(s, off, 64);

            if (l4 == 0) {
                float conf = 1.0f / s;
                int b = (int)ceilf(conf * (float)NB) - 1;
                b = b < 0 ? 0 : (b > NB - 1 ? NB - 1 : b);
                int cell = am * NB + b;
                atomicAdd(&hist[cell], conf);
                if (lab == am) atomicAdd(&hist[NCELLS + cell], 1.0f);
            }
        }
        __syncthreads();   // protect stage buffer before next overwrite
    }

    // flush per-block histogram
    for (int i = threadIdx.x; i < 2 * NCELLS; i += THREADS) {
        float v = hist[i];
        if (v != 0.0f) atomicAdd(&cellsums[i], v);
    }
}

__global__ void ece_final(const float* __restrict__ cellsums,
                          float invN, float* __restrict__ out) {
    __shared__ float red[256];
    float t = 0.0f;
    for (int i = threadIdx.x; i < NCELLS; i += blockDim.x)
        t += fabsf(cellsums[i] - cellsums[NCELLS + i]);
    red[threadIdx.x] = t;
    __syncthreads();
    for (int w = 128; w > 0; w >>= 1) {
        if (threadIdx.x < w) red[threadIdx.x] += red[threadIdx.x + w];
        __syncthreads();
    }
    if (threadIdx.x == 0) out[0] = red[0] * invN;
}

extern "C" void kernel_launch(void* const* d_in, const int* in_sizes, int n_in,
                              void* d_out, int out_size, void* d_ws, size_t ws_size,
                              hipStream_t stream) {
    const float* logits = (const float*)d_in[0];
    const int*   labels = (const int*)d_in[1];

    const int N = in_sizes[1];                     // 1,000,000
    const int ntiles = (N + ROWS - 1) / ROWS;      // 7813 (last tile: 64 rows)

    float* cellsums = (float*)d_ws;
    float* out = (float*)d_out;

    // 1) zero global cell accumulators (harness poisons ws, never re-zeroes)
    {
        int n = 2 * NCELLS;
        ece_zero<<<(n + 255) / 256, 256, 0, stream>>>(cellsums, n);
    }

    // 2) main pass: NT staging, 128-row tiles, 2 blocks/CU
    ece_main<<<GRID_MAIN, THREADS, 0, stream>>>(logits, labels, N, ntiles, cellsums);

    // 3) finalize
    ece_final<<<1, 256, 0, stream>>>(cellsums, 1.0f / (float)N, out);
}